// Round 1
// baseline (6986.877 us; speedup 1.0000x reference)
//
#include <hip/hip_runtime.h>

// GCN: out = A(A(relu(A(x W0^T)) ; relu)W1^T ...) — see reference.
// n = 100000 nodes, 1.6M edges, D 128/128/64, all fp32.

constexpr int NN = 100000;
constexpr int NE = 1600000;

// ---------------------------------------------------------------------------
// GEMM: C[n x DO] = act(H [,H2]) @ W^T   (W is DO x 128, row-major)
// ACT: 0 = identity, 1 = relu(H), 2 = relu(H) + relu(H2)  (residual fuse)
// Block tile: 64 rows x 64 cols, 256 threads, 4x4 outputs/thread.
// H and W staged TRANSPOSED into LDS ([k][r] / [k][c]) so the k-loop reads
// are ds_read_b128 with consecutive lanes on consecutive float4s (conflict-
// free: 2-way max, which is free on gfx950).
// ---------------------------------------------------------------------------
template<int DO, int ACT>
__global__ __launch_bounds__(256)
void gemm_kernel(const float* __restrict__ H, const float* __restrict__ H2,
                 const float* __restrict__ W, float* __restrict__ C, int n)
{
    __shared__ float sHT[128 * 64];   // [k][r]
    __shared__ float sWT[128 * 64];   // [k][c]
    const int tid = threadIdx.x;
    const int rowBase = blockIdx.x * 64;
    const int colBase = blockIdx.y * 64;

    // Stage H tile transposed. i -> (r = i&63, k4 = i>>6); global read is a
    // float4 of row r at k-chunk k4 (64 rows hit per instr; L1/L2 serve the
    // re-reads since the whole 32KB tile is consumed by this block).
    for (int i = tid; i < 64 * 32; i += 256) {
        const int r  = i & 63;
        const int k4 = i >> 6;
        const int row = rowBase + r;
        float4 h = make_float4(0.f, 0.f, 0.f, 0.f);
        if (row < n) {
            h = ((const float4*)H)[row * 32 + k4];
            if (ACT == 1) {
                h.x = fmaxf(h.x, 0.f); h.y = fmaxf(h.y, 0.f);
                h.z = fmaxf(h.z, 0.f); h.w = fmaxf(h.w, 0.f);
            } else if (ACT == 2) {
                const float4 g = ((const float4*)H2)[row * 32 + k4];
                h.x = fmaxf(h.x, 0.f) + fmaxf(g.x, 0.f);
                h.y = fmaxf(h.y, 0.f) + fmaxf(g.y, 0.f);
                h.z = fmaxf(h.z, 0.f) + fmaxf(g.z, 0.f);
                h.w = fmaxf(h.w, 0.f) + fmaxf(g.w, 0.f);
            }
        }
        // LDS writes: lanes have consecutive r -> consecutive banks, free.
        sHT[(k4 * 4 + 0) * 64 + r] = h.x;
        sHT[(k4 * 4 + 1) * 64 + r] = h.y;
        sHT[(k4 * 4 + 2) * 64 + r] = h.z;
        sHT[(k4 * 4 + 3) * 64 + r] = h.w;
    }
    // Stage W tile transposed (same pattern).
    for (int i = tid; i < 64 * 32; i += 256) {
        const int c  = i & 63;
        const int k4 = i >> 6;
        const float4 w = ((const float4*)W)[(colBase + c) * 32 + k4];
        sWT[(k4 * 4 + 0) * 64 + c] = w.x;
        sWT[(k4 * 4 + 1) * 64 + c] = w.y;
        sWT[(k4 * 4 + 2) * 64 + c] = w.z;
        sWT[(k4 * 4 + 3) * 64 + c] = w.w;
    }
    __syncthreads();

    const int rg = tid & 15;   // row group: rows rg*4 .. rg*4+3
    const int cg = tid >> 4;   // col group: cols cg*4 .. cg*4+3

    float acc[4][4];
    #pragma unroll
    for (int r = 0; r < 4; ++r)
        #pragma unroll
        for (int c = 0; c < 4; ++c) acc[r][c] = 0.f;

    #pragma unroll 8
    for (int k = 0; k < 128; ++k) {
        const float4 a = *(const float4*)&sHT[k * 64 + rg * 4];
        const float4 b = *(const float4*)&sWT[k * 64 + cg * 4];
        const float av[4] = {a.x, a.y, a.z, a.w};
        const float bv[4] = {b.x, b.y, b.z, b.w};
        #pragma unroll
        for (int r = 0; r < 4; ++r)
            #pragma unroll
            for (int c = 0; c < 4; ++c)
                acc[r][c] = fmaf(av[r], bv[c], acc[r][c]);
    }

    const int row0 = rowBase + rg * 4;
    #pragma unroll
    for (int r = 0; r < 4; ++r) {
        const int row = row0 + r;
        if (row < n) {
            const float4 o = make_float4(acc[r][0], acc[r][1], acc[r][2], acc[r][3]);
            *(float4*)&C[(size_t)row * DO + colBase + cg * 4] = o;
        }
    }
}

// ---------------------------------------------------------------------------
// SpMM D=128: y[row[e]] += val[e] * h[col[e]], 32 lanes/edge, float4/lane,
// atomic f32 scatter. 8 edges per 256-thread block.
// ---------------------------------------------------------------------------
__global__ __launch_bounds__(256)
void spmm128_kernel(const int* __restrict__ erow, const int* __restrict__ ecol,
                    const float* __restrict__ eval, const float* __restrict__ H,
                    float* __restrict__ Y)
{
    const int lane = threadIdx.x & 31;
    const int e = blockIdx.x * 8 + (threadIdx.x >> 5);
    if (e >= NE) return;
    const int r = erow[e];
    const int c = ecol[e];
    const float v = eval[e];
    const float4 h = ((const float4*)H)[c * 32 + lane];
    float* y = Y + (size_t)r * 128 + lane * 4;
    atomicAdd(y + 0, v * h.x);
    atomicAdd(y + 1, v * h.y);
    atomicAdd(y + 2, v * h.z);
    atomicAdd(y + 3, v * h.w);
}

// SpMM D=64: 16 lanes/edge, 16 edges per block.
__global__ __launch_bounds__(256)
void spmm64_kernel(const int* __restrict__ erow, const int* __restrict__ ecol,
                   const float* __restrict__ eval, const float* __restrict__ H,
                   float* __restrict__ Y)
{
    const int lane = threadIdx.x & 15;
    const int e = blockIdx.x * 16 + (threadIdx.x >> 4);
    if (e >= NE) return;
    const int r = erow[e];
    const int c = ecol[e];
    const float v = eval[e];
    const float4 h = ((const float4*)H)[c * 16 + lane];
    float* y = Y + (size_t)r * 64 + lane * 4;
    atomicAdd(y + 0, v * h.x);
    atomicAdd(y + 1, v * h.y);
    atomicAdd(y + 2, v * h.z);
    atomicAdd(y + 3, v * h.w);
}

extern "C" void kernel_launch(void* const* d_in, const int* in_sizes, int n_in,
                              void* d_out, int out_size, void* d_ws, size_t ws_size,
                              hipStream_t stream) {
    const float* x    = (const float*)d_in[0];   // (1, N, 128)
    const int*   erow = (const int*)  d_in[1];
    const int*   ecol = (const int*)  d_in[2];
    const float* eval = (const float*)d_in[3];
    const float* W0   = (const float*)d_in[4];   // 128x128
    const float* W1   = (const float*)d_in[5];   // 128x128
    const float* W2   = (const float*)d_in[6];   // 64x128
    float* out = (float*)d_out;                  // N x 64

    char* ws = (char*)d_ws;
    const size_t BUF = (size_t)NN * 128 * sizeof(float);  // 51.2 MB
    float* t     = (float*)(ws);            // t0 / t1 / t2 (reused)
    float* h1raw = (float*)(ws + BUF);      // pre-relu layer-1 spmm result
    float* h2raw = (float*)(ws + 2 * BUF);  // pre-relu layer-2 spmm result

    const dim3 blk(256);
    const int gemmBlocks = (NN + 63) / 64;   // 1563

    // t0 = x @ W0^T
    gemm_kernel<128, 0><<<dim3(gemmBlocks, 2), blk, 0, stream>>>(x, nullptr, W0, t, NN);
    // h1raw = A @ t0
    hipMemsetAsync(h1raw, 0, BUF, stream);
    spmm128_kernel<<<NE / 8, blk, 0, stream>>>(erow, ecol, eval, t, h1raw);
    // t1 = relu(h1raw) @ W1^T
    gemm_kernel<128, 1><<<dim3(gemmBlocks, 2), blk, 0, stream>>>(h1raw, nullptr, W1, t, NN);
    // h2raw = A @ t1
    hipMemsetAsync(h2raw, 0, BUF, stream);
    spmm128_kernel<<<NE / 8, blk, 0, stream>>>(erow, ecol, eval, t, h2raw);
    // t2 = (relu(h2raw) + relu(h1raw)) @ W2^T   [h2 = relu(A t1) + h1 residual]
    gemm_kernel<64, 2><<<dim3(gemmBlocks, 1), blk, 0, stream>>>(h2raw, h1raw, W2, t, NN);
    // out = A @ t2
    hipMemsetAsync(out, 0, (size_t)NN * 64 * sizeof(float), stream);
    spmm64_kernel<<<NE / 16, blk, 0, stream>>>(erow, ecol, eval, t, out);
}

// Round 2
// 744.566 us; speedup vs baseline: 9.3838x; 9.3838x over previous
//
#include <hip/hip_runtime.h>

// GCN on MI355X. n=100000 nodes, 1.6M edges, D 128/128/64, fp32.
// Round 2: replace atomic-scatter SpMM with per-launch CSR build
// (counting sort) + gather SpMM (one 32-lane group per row, no atomics
// on the feature data).

constexpr int NN = 100000;
constexpr int NE = 1600000;
constexpr int PAD = 100352;            // NN padded to multiple of 1024
constexpr int NBLK = PAD / 1024;       // 98 scan blocks

// ---------------------------------------------------------------------------
// GEMM: C[n x DO] = act(H [,H2]) @ W^T   (W is DO x 128, row-major)
// ACT: 0 = identity, 1 = relu(H), 2 = relu(H)+relu(H2) (residual fuse)
// 64x64 tile, 256 threads, 4x4 accum/thread, H/W staged transposed in LDS.
// ---------------------------------------------------------------------------
template<int DO, int ACT>
__global__ __launch_bounds__(256)
void gemm_kernel(const float* __restrict__ H, const float* __restrict__ H2,
                 const float* __restrict__ W, float* __restrict__ C, int n)
{
    __shared__ float sHT[128 * 64];   // [k][r]
    __shared__ float sWT[128 * 64];   // [k][c]
    const int tid = threadIdx.x;
    const int rowBase = blockIdx.x * 64;
    const int colBase = blockIdx.y * 64;

    for (int i = tid; i < 64 * 32; i += 256) {
        const int r  = i & 63;
        const int k4 = i >> 6;
        const int row = rowBase + r;
        float4 h = make_float4(0.f, 0.f, 0.f, 0.f);
        if (row < n) {
            h = ((const float4*)H)[row * 32 + k4];
            if (ACT == 1) {
                h.x = fmaxf(h.x, 0.f); h.y = fmaxf(h.y, 0.f);
                h.z = fmaxf(h.z, 0.f); h.w = fmaxf(h.w, 0.f);
            } else if (ACT == 2) {
                const float4 g = ((const float4*)H2)[row * 32 + k4];
                h.x = fmaxf(h.x, 0.f) + fmaxf(g.x, 0.f);
                h.y = fmaxf(h.y, 0.f) + fmaxf(g.y, 0.f);
                h.z = fmaxf(h.z, 0.f) + fmaxf(g.z, 0.f);
                h.w = fmaxf(h.w, 0.f) + fmaxf(g.w, 0.f);
            }
        }
        sHT[(k4 * 4 + 0) * 64 + r] = h.x;
        sHT[(k4 * 4 + 1) * 64 + r] = h.y;
        sHT[(k4 * 4 + 2) * 64 + r] = h.z;
        sHT[(k4 * 4 + 3) * 64 + r] = h.w;
    }
    for (int i = tid; i < 64 * 32; i += 256) {
        const int c  = i & 63;
        const int k4 = i >> 6;
        const float4 w = ((const float4*)W)[(colBase + c) * 32 + k4];
        sWT[(k4 * 4 + 0) * 64 + c] = w.x;
        sWT[(k4 * 4 + 1) * 64 + c] = w.y;
        sWT[(k4 * 4 + 2) * 64 + c] = w.z;
        sWT[(k4 * 4 + 3) * 64 + c] = w.w;
    }
    __syncthreads();

    const int rg = tid & 15;
    const int cg = tid >> 4;

    float acc[4][4];
    #pragma unroll
    for (int r = 0; r < 4; ++r)
        #pragma unroll
        for (int c = 0; c < 4; ++c) acc[r][c] = 0.f;

    #pragma unroll 8
    for (int k = 0; k < 128; ++k) {
        const float4 a = *(const float4*)&sHT[k * 64 + rg * 4];
        const float4 b = *(const float4*)&sWT[k * 64 + cg * 4];
        const float av[4] = {a.x, a.y, a.z, a.w};
        const float bv[4] = {b.x, b.y, b.z, b.w};
        #pragma unroll
        for (int r = 0; r < 4; ++r)
            #pragma unroll
            for (int c = 0; c < 4; ++c)
                acc[r][c] = fmaf(av[r], bv[c], acc[r][c]);
    }

    const int row0 = rowBase + rg * 4;
    #pragma unroll
    for (int r = 0; r < 4; ++r) {
        const int row = row0 + r;
        if (row < n) {
            const float4 o = make_float4(acc[r][0], acc[r][1], acc[r][2], acc[r][3]);
            *(float4*)&C[(size_t)row * DO + colBase + cg * 4] = o;
        }
    }
}

// ---------------------------------------------------------------------------
// CSR build: histogram -> block scan -> scan of block sums -> add offsets
// -> scatter-permute (col,val).
// ---------------------------------------------------------------------------
__global__ __launch_bounds__(256)
void hist_kernel(const int* __restrict__ erow, int* __restrict__ counts)
{
    const int e = blockIdx.x * 256 + threadIdx.x;
    if (e < NE) atomicAdd(&counts[erow[e]], 1);
}

// Per-1024-chunk exclusive scan (256 thr x 4 elems), emits chunk totals.
__global__ __launch_bounds__(256)
void scan1_kernel(const int* __restrict__ counts, int* __restrict__ offs,
                  int* __restrict__ blockSums)
{
    __shared__ int sdata[256];
    const int tid = threadIdx.x;
    const int base = blockIdx.x * 1024 + tid * 4;
    const int4 v = *(const int4*)&counts[base];
    const int tsum = v.x + v.y + v.z + v.w;
    sdata[tid] = tsum;
    __syncthreads();
    #pragma unroll
    for (int off = 1; off < 256; off <<= 1) {
        const int val = (tid >= off) ? sdata[tid - off] : 0;
        __syncthreads();
        sdata[tid] += val;
        __syncthreads();
    }
    const int excl = sdata[tid] - tsum;
    offs[base + 0] = excl;
    offs[base + 1] = excl + v.x;
    offs[base + 2] = excl + v.x + v.y;
    offs[base + 3] = excl + v.x + v.y + v.z;
    if (tid == 255) blockSums[blockIdx.x] = sdata[255];
}

// Exclusive scan of NBLK (=98) block sums, single 128-thread block.
__global__ __launch_bounds__(128)
void scan2_kernel(int* __restrict__ blockSums)
{
    __shared__ int sdata[128];
    const int tid = threadIdx.x;
    const int v = (tid < NBLK) ? blockSums[tid] : 0;
    sdata[tid] = v;
    __syncthreads();
    #pragma unroll
    for (int off = 1; off < 128; off <<= 1) {
        const int val = (tid >= off) ? sdata[tid - off] : 0;
        __syncthreads();
        sdata[tid] += val;
        __syncthreads();
    }
    if (tid < NBLK) blockSums[tid] = sdata[tid] - v;  // exclusive
}

// Add chunk offsets; also initialize the scatter cursors.
__global__ __launch_bounds__(256)
void scan3_kernel(int* __restrict__ offs, const int* __restrict__ blockSums,
                  int* __restrict__ cursor)
{
    const int i = blockIdx.x * 256 + threadIdx.x;
    if (i < PAD) {
        const int o = offs[i] + blockSums[i >> 10];
        offs[i] = o;
        cursor[i] = o;
    }
}

__global__ __launch_bounds__(256)
void scatter_kernel(const int* __restrict__ erow, const int* __restrict__ ecol,
                    const float* __restrict__ eval, int* __restrict__ cursor,
                    int* __restrict__ pcol, float* __restrict__ pval)
{
    const int e = blockIdx.x * 256 + threadIdx.x;
    if (e < NE) {
        const int r = erow[e];
        const int pos = atomicAdd(&cursor[r], 1);
        pcol[pos] = ecol[e];
        pval[pos] = eval[e];
    }
}

// ---------------------------------------------------------------------------
// CSR SpMM: one 32-lane (D=128) / 16-lane (D=64) group per row, register
// accumulation, single coalesced float4 store per row. No atomics, no memset.
// Edge loop unrolled x2 with dual accumulators to shorten the dependent
// gather chain.
// ---------------------------------------------------------------------------
__global__ __launch_bounds__(256)
void spmm_csr128(const int* __restrict__ offs, const int* __restrict__ pcol,
                 const float* __restrict__ pval, const float* __restrict__ H,
                 float* __restrict__ Y)
{
    const int lane = threadIdx.x & 31;
    const int row = blockIdx.x * 8 + (threadIdx.x >> 5);
    if (row >= NN) return;
    const int s = offs[row];
    const int t = offs[row + 1];
    const float4* __restrict__ H4 = (const float4*)H;

    float4 acc0 = make_float4(0.f, 0.f, 0.f, 0.f);
    float4 acc1 = make_float4(0.f, 0.f, 0.f, 0.f);
    int e = s;
    for (; e + 1 < t; e += 2) {
        const int c0 = pcol[e];
        const int c1 = pcol[e + 1];
        const float v0 = pval[e];
        const float v1 = pval[e + 1];
        const float4 h0 = H4[c0 * 32 + lane];
        const float4 h1 = H4[c1 * 32 + lane];
        acc0.x = fmaf(v0, h0.x, acc0.x); acc0.y = fmaf(v0, h0.y, acc0.y);
        acc0.z = fmaf(v0, h0.z, acc0.z); acc0.w = fmaf(v0, h0.w, acc0.w);
        acc1.x = fmaf(v1, h1.x, acc1.x); acc1.y = fmaf(v1, h1.y, acc1.y);
        acc1.z = fmaf(v1, h1.z, acc1.z); acc1.w = fmaf(v1, h1.w, acc1.w);
    }
    if (e < t) {
        const int c0 = pcol[e];
        const float v0 = pval[e];
        const float4 h0 = H4[c0 * 32 + lane];
        acc0.x = fmaf(v0, h0.x, acc0.x); acc0.y = fmaf(v0, h0.y, acc0.y);
        acc0.z = fmaf(v0, h0.z, acc0.z); acc0.w = fmaf(v0, h0.w, acc0.w);
    }
    acc0.x += acc1.x; acc0.y += acc1.y; acc0.z += acc1.z; acc0.w += acc1.w;
    ((float4*)Y)[row * 32 + lane] = acc0;
}

__global__ __launch_bounds__(256)
void spmm_csr64(const int* __restrict__ offs, const int* __restrict__ pcol,
                const float* __restrict__ pval, const float* __restrict__ H,
                float* __restrict__ Y)
{
    const int lane = threadIdx.x & 15;
    const int row = blockIdx.x * 16 + (threadIdx.x >> 4);
    if (row >= NN) return;
    const int s = offs[row];
    const int t = offs[row + 1];
    const float4* __restrict__ H4 = (const float4*)H;

    float4 acc0 = make_float4(0.f, 0.f, 0.f, 0.f);
    float4 acc1 = make_float4(0.f, 0.f, 0.f, 0.f);
    int e = s;
    for (; e + 1 < t; e += 2) {
        const int c0 = pcol[e];
        const int c1 = pcol[e + 1];
        const float v0 = pval[e];
        const float v1 = pval[e + 1];
        const float4 h0 = H4[c0 * 16 + lane];
        const float4 h1 = H4[c1 * 16 + lane];
        acc0.x = fmaf(v0, h0.x, acc0.x); acc0.y = fmaf(v0, h0.y, acc0.y);
        acc0.z = fmaf(v0, h0.z, acc0.z); acc0.w = fmaf(v0, h0.w, acc0.w);
        acc1.x = fmaf(v1, h1.x, acc1.x); acc1.y = fmaf(v1, h1.y, acc1.y);
        acc1.z = fmaf(v1, h1.z, acc1.z); acc1.w = fmaf(v1, h1.w, acc1.w);
    }
    if (e < t) {
        const int c0 = pcol[e];
        const float v0 = pval[e];
        const float4 h0 = H4[c0 * 16 + lane];
        acc0.x = fmaf(v0, h0.x, acc0.x); acc0.y = fmaf(v0, h0.y, acc0.y);
        acc0.z = fmaf(v0, h0.z, acc0.z); acc0.w = fmaf(v0, h0.w, acc0.w);
    }
    acc0.x += acc1.x; acc0.y += acc1.y; acc0.z += acc1.z; acc0.w += acc1.w;
    ((float4*)Y)[row * 16 + lane] = acc0;
}

extern "C" void kernel_launch(void* const* d_in, const int* in_sizes, int n_in,
                              void* d_out, int out_size, void* d_ws, size_t ws_size,
                              hipStream_t stream) {
    const float* x    = (const float*)d_in[0];
    const int*   erow = (const int*)  d_in[1];
    const int*   ecol = (const int*)  d_in[2];
    const float* eval = (const float*)d_in[3];
    const float* W0   = (const float*)d_in[4];
    const float* W1   = (const float*)d_in[5];
    const float* W2   = (const float*)d_in[6];
    float* out = (float*)d_out;

    char* ws = (char*)d_ws;
    const size_t BUF = (size_t)NN * 128 * sizeof(float);   // 51,200,000 B
    float* t      = (float*)(ws);
    float* h1raw  = (float*)(ws + BUF);
    float* h2raw  = (float*)(ws + 2 * BUF);
    char*  p      = ws + 3 * BUF;
    int*   offs   = (int*)p;              p += (size_t)PAD * 4;       // 401,408
    int*   cursor = (int*)p;              p += (size_t)PAD * 4;       // doubles as counts
    int*   bsums  = (int*)p;              p += 512;
    int*   pcol   = (int*)p;              p += (size_t)NE * 4;        // 6,400,000
    float* pval   = (float*)p;

    const dim3 blk(256);
    const int gemmBlocks = (NN + 63) / 64;

    // ---- CSR build (amortized over the 3 SpMMs) ----
    hipMemsetAsync(cursor, 0, (size_t)PAD * 4, stream);               // counts = 0
    hist_kernel   <<<(NE + 255) / 256, blk, 0, stream>>>(erow, cursor);
    scan1_kernel  <<<NBLK, blk, 0, stream>>>(cursor, offs, bsums);
    scan2_kernel  <<<1, 128, 0, stream>>>(bsums);
    scan3_kernel  <<<(PAD + 255) / 256, blk, 0, stream>>>(offs, bsums, cursor);
    scatter_kernel<<<(NE + 255) / 256, blk, 0, stream>>>(erow, ecol, eval,
                                                         cursor, pcol, pval);

    // ---- layers ----
    gemm_kernel<128, 0><<<dim3(gemmBlocks, 2), blk, 0, stream>>>(x, nullptr, W0, t, NN);
    spmm_csr128<<<(NN + 7) / 8, blk, 0, stream>>>(offs, pcol, pval, t, h1raw);
    gemm_kernel<128, 1><<<dim3(gemmBlocks, 2), blk, 0, stream>>>(h1raw, nullptr, W1, t, NN);
    spmm_csr128<<<(NN + 7) / 8, blk, 0, stream>>>(offs, pcol, pval, t, h2raw);
    gemm_kernel<64, 2><<<dim3(gemmBlocks, 1), blk, 0, stream>>>(h2raw, h1raw, W2, t, NN);
    spmm_csr64 <<<(NN + 15) / 16, blk, 0, stream>>>(offs, pcol, pval, t, out);
}

// Round 3
// 538.856 us; speedup vs baseline: 12.9661x; 1.3818x over previous
//
#include <hip/hip_runtime.h>

// GCN on MI355X (gfx950). n=100000, 1.6M edges, D 128/128/64.
// Round 3: bf16 intermediates. GEMMs use mfma_f32_16x16x32_bf16 (fp32 acc),
// SpMM gathers bf16 rows (half the fetch bytes), relu / relu+residual fused
// into SpMM epilogues. CSR build as round 2, scatter packs (col,val) int2.

typedef unsigned int u32;
typedef unsigned short u16;
typedef __attribute__((ext_vector_type(8))) short bf16x8;
typedef __attribute__((ext_vector_type(4))) float f32x4;

constexpr int NN = 100000;
constexpr int NE = 1600000;
constexpr int PAD = 100352;            // NN padded to multiple of 1024
constexpr int NBLK = PAD / 1024;       // 98 scan blocks

__device__ __forceinline__ u16 f2bf(float f) {   // RNE round to bf16
    u32 x = __float_as_uint(f);
    x += 0x7fffu + ((x >> 16) & 1u);
    return (u16)(x >> 16);
}

// ---------------------------------------------------------------------------
// GEMM: C_bf16[n x DO] = H @ W^T.  W pre-converted to bf16 (row-major DOx128).
// Block = 256 thr = 4 waves; wave w owns rows blockIdx*64 + w*16 .. +15.
// A-frags (4 K-chunks of 32) in regs; B-frags straight from global (W is
// 32KB, L1/L2-resident). Epilogue: bf16 through LDS for a contiguous-4KB
// per-wave coalesced store.
// MFMA layouts (HW-verified per guide): A[m=lane&15][k=(lane>>4)*8+j],
// B[k=(lane>>4)*8+j][n=lane&15], D: col=lane&15, row=(lane>>4)*4+reg.
// ---------------------------------------------------------------------------
template<int DO, bool FP32IN>
__global__ __launch_bounds__(256)
void gemm_mfma(const void* __restrict__ Hin, const u16* __restrict__ Wb,
               u16* __restrict__ Cb, int n)
{
    constexpr int PADW = DO + 8;       // pad LDS row to break pow-2 stride
    __shared__ u16 sC[4 * 16 * PADW];
    const int tid  = threadIdx.x;
    const int w    = tid >> 6;
    const int lane = tid & 63;
    const int m    = lane & 15;
    const int q    = lane >> 4;
    const int row  = blockIdx.x * 64 + w * 16 + m;

    bf16x8 afrag[4];
    #pragma unroll
    for (int kc = 0; kc < 4; ++kc) {
        bf16x8 a = {0, 0, 0, 0, 0, 0, 0, 0};
        if (row < n) {
            if (FP32IN) {
                const float* H = (const float*)Hin;
                const float4* p = (const float4*)(H + (size_t)row * 128 + kc * 32 + q * 8);
                const float4 u0 = p[0];
                const float4 u1 = p[1];
                a[0] = (short)f2bf(u0.x); a[1] = (short)f2bf(u0.y);
                a[2] = (short)f2bf(u0.z); a[3] = (short)f2bf(u0.w);
                a[4] = (short)f2bf(u1.x); a[5] = (short)f2bf(u1.y);
                a[6] = (short)f2bf(u1.z); a[7] = (short)f2bf(u1.w);
            } else {
                const u16* H = (const u16*)Hin;
                a = *(const bf16x8*)(H + (size_t)row * 128 + kc * 32 + q * 8);
            }
        }
        afrag[kc] = a;
    }

    #pragma unroll 4
    for (int ct = 0; ct < DO / 16; ++ct) {
        f32x4 acc = {0.f, 0.f, 0.f, 0.f};
        #pragma unroll
        for (int kc = 0; kc < 4; ++kc) {
            const bf16x8 b = *(const bf16x8*)(Wb + (ct * 16 + m) * 128 + kc * 32 + q * 8);
            acc = __builtin_amdgcn_mfma_f32_16x16x32_bf16(afrag[kc], b, acc, 0, 0, 0);
        }
        #pragma unroll
        for (int r = 0; r < 4; ++r)
            sC[(w * 16 + q * 4 + r) * PADW + ct * 16 + m] = f2bf(acc[r]);
    }
    __syncthreads();

    // Per-wave 16 rows x DO bf16 tile is contiguous 2*16*DO bytes in global.
    const int g    = lane >> 2;                 // local row 0..15
    const int cb   = (lane & 3) * (DO / 4);     // start col (elems)
    const int grow = blockIdx.x * 64 + w * 16 + g;
    if (grow < n) {
        #pragma unroll
        for (int i = 0; i < DO / 32; ++i) {
            const int4 v = *(const int4*)&sC[(w * 16 + g) * PADW + cb + i * 8];
            *(int4*)(Cb + (size_t)grow * DO + cb + i * 8) = v;
        }
    }
}

// ---------------------------------------------------------------------------
// Weight fp32 -> bf16 (one-time per launch; 40960 elems total).
// ---------------------------------------------------------------------------
__global__ __launch_bounds__(256)
void wcvt_kernel(const float* __restrict__ W0, const float* __restrict__ W1,
                 const float* __restrict__ W2, u16* __restrict__ w0b,
                 u16* __restrict__ w1b, u16* __restrict__ w2b)
{
    const int i = blockIdx.x * 256 + threadIdx.x;
    if (i < 128 * 128) { w0b[i] = f2bf(W0[i]); w1b[i] = f2bf(W1[i]); }
    if (i < 64 * 128)  { w2b[i] = f2bf(W2[i]); }
}

// ---------------------------------------------------------------------------
// CSR build: histogram -> 2-level exclusive scan -> scatter (col,val) int2.
// ---------------------------------------------------------------------------
__global__ __launch_bounds__(256)
void hist_kernel(const int* __restrict__ erow, int* __restrict__ counts)
{
    const int e = blockIdx.x * 256 + threadIdx.x;
    if (e < NE) atomicAdd(&counts[erow[e]], 1);
}

__global__ __launch_bounds__(256)
void scan1_kernel(const int* __restrict__ counts, int* __restrict__ offs,
                  int* __restrict__ blockSums)
{
    __shared__ int sdata[256];
    const int tid = threadIdx.x;
    const int base = blockIdx.x * 1024 + tid * 4;
    const int4 v = *(const int4*)&counts[base];
    const int tsum = v.x + v.y + v.z + v.w;
    sdata[tid] = tsum;
    __syncthreads();
    #pragma unroll
    for (int off = 1; off < 256; off <<= 1) {
        const int val = (tid >= off) ? sdata[tid - off] : 0;
        __syncthreads();
        sdata[tid] += val;
        __syncthreads();
    }
    const int excl = sdata[tid] - tsum;
    offs[base + 0] = excl;
    offs[base + 1] = excl + v.x;
    offs[base + 2] = excl + v.x + v.y;
    offs[base + 3] = excl + v.x + v.y + v.z;
    if (tid == 255) blockSums[blockIdx.x] = sdata[255];
}

__global__ __launch_bounds__(128)
void scan2_kernel(int* __restrict__ blockSums)
{
    __shared__ int sdata[128];
    const int tid = threadIdx.x;
    const int v = (tid < NBLK) ? blockSums[tid] : 0;
    sdata[tid] = v;
    __syncthreads();
    #pragma unroll
    for (int off = 1; off < 128; off <<= 1) {
        const int val = (tid >= off) ? sdata[tid - off] : 0;
        __syncthreads();
        sdata[tid] += val;
        __syncthreads();
    }
    if (tid < NBLK) blockSums[tid] = sdata[tid] - v;
}

__global__ __launch_bounds__(256)
void scan3_kernel(int* __restrict__ offs, const int* __restrict__ blockSums,
                  int* __restrict__ cursor)
{
    const int i = blockIdx.x * 256 + threadIdx.x;
    if (i < PAD) {
        const int o = offs[i] + blockSums[i >> 10];
        offs[i] = o;
        cursor[i] = o;
    }
}

__global__ __launch_bounds__(256)
void scatter_kernel(const int* __restrict__ erow, const int* __restrict__ ecol,
                    const float* __restrict__ eval, int* __restrict__ cursor,
                    int2* __restrict__ pce)
{
    const int e = blockIdx.x * 256 + threadIdx.x;
    if (e < NE) {
        const int r = erow[e];
        const int pos = atomicAdd(&cursor[r], 1);
        pce[pos] = make_int2(ecol[e], __float_as_int(eval[e]));
    }
}

// ---------------------------------------------------------------------------
// CSR SpMM over bf16 features, fp32 accumulate. 16 lanes/row, 16 rows/block.
// MODE 1: Y_bf16 = relu(A H)                      (layer 1)
// MODE 2: Y_bf16 = relu(A H) + Res_bf16           (layer 2, residual fuse)
// MODE 3: Y_f32  = A H                            (layer 3, final output)
// ---------------------------------------------------------------------------
template<int LPC>
__device__ __forceinline__ void load_row(const u16* p, u32* u) {
    if constexpr (LPC == 8) {
        const uint4 t = *(const uint4*)p;
        u[0] = t.x; u[1] = t.y; u[2] = t.z; u[3] = t.w;
    } else {
        const uint2 t = *(const uint2*)p;
        u[0] = t.x; u[1] = t.y;
    }
}

template<int D, int MODE>
__global__ __launch_bounds__(256)
void spmm_csr(const int* __restrict__ offs, const int2* __restrict__ pce,
              const u16* __restrict__ Hb, void* __restrict__ Yv,
              const u16* __restrict__ Res)
{
    constexpr int LPC = D / 16;        // bf16 elems per lane
    const int ln  = threadIdx.x & 15;
    const int row = blockIdx.x * 16 + (threadIdx.x >> 4);
    if (row >= NN) return;
    const int s = offs[row];
    const int t = offs[row + 1];
    const u16* hbase = Hb + ln * LPC;

    float a0[LPC], a1[LPC];
    #pragma unroll
    for (int j = 0; j < LPC; ++j) { a0[j] = 0.f; a1[j] = 0.f; }

    int e = s;
    for (; e + 1 < t; e += 2) {
        const int2 e0 = pce[e];
        const int2 e1 = pce[e + 1];
        const float v0 = __int_as_float(e0.y);
        const float v1 = __int_as_float(e1.y);
        u32 u0[LPC / 2], u1v[LPC / 2];
        load_row<LPC>(hbase + (size_t)e0.x * D, u0);
        load_row<LPC>(hbase + (size_t)e1.x * D, u1v);
        #pragma unroll
        for (int j = 0; j < LPC / 2; ++j) {
            a0[2*j]   = fmaf(v0, __uint_as_float(u0[j] << 16),         a0[2*j]);
            a0[2*j+1] = fmaf(v0, __uint_as_float(u0[j] & 0xffff0000u), a0[2*j+1]);
            a1[2*j]   = fmaf(v1, __uint_as_float(u1v[j] << 16),         a1[2*j]);
            a1[2*j+1] = fmaf(v1, __uint_as_float(u1v[j] & 0xffff0000u), a1[2*j+1]);
        }
    }
    if (e < t) {
        const int2 e0 = pce[e];
        const float v0 = __int_as_float(e0.y);
        u32 u0[LPC / 2];
        load_row<LPC>(hbase + (size_t)e0.x * D, u0);
        #pragma unroll
        for (int j = 0; j < LPC / 2; ++j) {
            a0[2*j]   = fmaf(v0, __uint_as_float(u0[j] << 16),         a0[2*j]);
            a0[2*j+1] = fmaf(v0, __uint_as_float(u0[j] & 0xffff0000u), a0[2*j+1]);
        }
    }
    #pragma unroll
    for (int j = 0; j < LPC; ++j) a0[j] += a1[j];

    if constexpr (MODE == 3) {
        float* Y = (float*)Yv;
        *(float4*)(Y + (size_t)row * D + ln * LPC) =
            make_float4(a0[0], a0[1], a0[2], a0[3]);
    } else {
        if constexpr (MODE == 2) {
            u32 r[LPC / 2];
            load_row<LPC>(Res + (size_t)row * D + ln * LPC, r);
            #pragma unroll
            for (int j = 0; j < LPC / 2; ++j) {
                a0[2*j]   = fmaxf(a0[2*j],   0.f) + __uint_as_float(r[j] << 16);
                a0[2*j+1] = fmaxf(a0[2*j+1], 0.f) + __uint_as_float(r[j] & 0xffff0000u);
            }
        } else {
            #pragma unroll
            for (int j = 0; j < LPC; ++j) a0[j] = fmaxf(a0[j], 0.f);
        }
        u32 o[LPC / 2];
        #pragma unroll
        for (int j = 0; j < LPC / 2; ++j)
            o[j] = (u32)f2bf(a0[2*j]) | ((u32)f2bf(a0[2*j+1]) << 16);
        u16* Y = (u16*)Yv;
        if constexpr (LPC == 8)
            *(uint4*)(Y + (size_t)row * D + ln * LPC) = make_uint4(o[0], o[1], o[2], o[3]);
        else
            *(uint2*)(Y + (size_t)row * D + ln * LPC) = make_uint2(o[0], o[1]);
    }
}

extern "C" void kernel_launch(void* const* d_in, const int* in_sizes, int n_in,
                              void* d_out, int out_size, void* d_ws, size_t ws_size,
                              hipStream_t stream) {
    const float* x    = (const float*)d_in[0];
    const int*   erow = (const int*)  d_in[1];
    const int*   ecol = (const int*)  d_in[2];
    const float* eval = (const float*)d_in[3];
    const float* W0   = (const float*)d_in[4];
    const float* W1   = (const float*)d_in[5];
    const float* W2   = (const float*)d_in[6];
    float* out = (float*)d_out;

    char* p = (char*)d_ws;
    const size_t BUFB = (size_t)NN * 128 * sizeof(u16);   // 25.6 MB
    u16* tb    = (u16*)p;  p += BUFB;     // GEMM outputs (t0b/t1b/t2b reused)
    u16* h1b   = (u16*)p;  p += BUFB;     // relu(A t0), post-relu
    u16* h2b   = (u16*)p;  p += BUFB;     // relu(A t1) + h1b
    u16* w0b   = (u16*)p;  p += 128 * 128 * 2;
    u16* w1b   = (u16*)p;  p += 128 * 128 * 2;
    u16* w2b   = (u16*)p;  p += 64 * 128 * 2;
    int* offs   = (int*)p; p += (size_t)PAD * 4;
    int* cursor = (int*)p; p += (size_t)PAD * 4;          // doubles as counts
    int* bsums  = (int*)p; p += 512;
    int2* pce   = (int2*)p;                               // NE * 8 B

    const dim3 blk(256);
    const int gemmBlocks = (NN + 63) / 64;     // 1563
    const int spmmBlocks = (NN + 15) / 16;     // 6250
    const int edgeBlocks = (NE + 255) / 256;   // 6250

    // ---- CSR build + weight convert ----
    hipMemsetAsync(cursor, 0, (size_t)PAD * 4, stream);
    hist_kernel   <<<edgeBlocks, blk, 0, stream>>>(erow, cursor);
    scan1_kernel  <<<NBLK, blk, 0, stream>>>(cursor, offs, bsums);
    scan2_kernel  <<<1, 128, 0, stream>>>(bsums);
    scan3_kernel  <<<(PAD + 255) / 256, blk, 0, stream>>>(offs, bsums, cursor);
    scatter_kernel<<<edgeBlocks, blk, 0, stream>>>(erow, ecol, eval, cursor, pce);
    wcvt_kernel   <<<64, blk, 0, stream>>>(W0, W1, W2, w0b, w1b, w2b);

    // ---- layers ----
    gemm_mfma<128, true ><<<gemmBlocks, blk, 0, stream>>>(x,   w0b, tb, NN);
    spmm_csr<128, 1><<<spmmBlocks, blk, 0, stream>>>(offs, pce, tb, h1b, nullptr);
    gemm_mfma<128, false><<<gemmBlocks, blk, 0, stream>>>(h1b, w1b, tb, NN);
    spmm_csr<128, 2><<<spmmBlocks, blk, 0, stream>>>(offs, pce, tb, h2b, h1b);
    gemm_mfma<64,  false><<<gemmBlocks, blk, 0, stream>>>(h2b, w2b, tb, NN);
    spmm_csr<64, 3><<<spmmBlocks, blk, 0, stream>>>(offs, pce, tb, out, nullptr);
}

// Round 4
// 467.158 us; speedup vs baseline: 14.9561x; 1.1535x over previous
//
#include <hip/hip_runtime.h>

// GCN on MI355X (gfx950). n=100000, 1.6M edges, D 128/128/64.
// Round 4: two-phase bucketed CSR build. Phase 1 partitions edges into 196
// buckets of 512 rows with per-block contiguous reservations (write-
// amplification ~1 instead of 8x), folding the row histogram into the same
// pass. Phase 2: one WG per bucket, LDS row cursors, single-CU writes into
// the bucket's contiguous CSR slice. GEMM (bf16 MFMA) and SpMM unchanged.

typedef unsigned int u32;
typedef unsigned short u16;
typedef __attribute__((ext_vector_type(8))) short bf16x8;
typedef __attribute__((ext_vector_type(4))) float f32x4;

constexpr int NN = 100000;
constexpr int NE = 1600000;
constexpr int PAD = 100352;            // NN padded: 196 * 512
constexpr int NBUCK = 196;             // buckets of 512 rows
constexpr int BCAP = 10240;            // per-bucket capacity (mean 8163, +23 sigma)
constexpr int EPB = 4096;              // edges per phase-1 block

__device__ __forceinline__ u16 f2bf(float f) {   // RNE round to bf16
    u32 x = __float_as_uint(f);
    x += 0x7fffu + ((x >> 16) & 1u);
    return (u16)(x >> 16);
}

// ---------------------------------------------------------------------------
// GEMM: C_bf16[n x DO] = H @ W^T, mfma_f32_16x16x32_bf16, fp32 accum.
// ---------------------------------------------------------------------------
template<int DO, bool FP32IN>
__global__ __launch_bounds__(256)
void gemm_mfma(const void* __restrict__ Hin, const u16* __restrict__ Wb,
               u16* __restrict__ Cb, int n)
{
    constexpr int PADW = DO + 8;
    __shared__ u16 sC[4 * 16 * PADW];
    const int tid  = threadIdx.x;
    const int w    = tid >> 6;
    const int lane = tid & 63;
    const int m    = lane & 15;
    const int q    = lane >> 4;
    const int row  = blockIdx.x * 64 + w * 16 + m;

    bf16x8 afrag[4];
    #pragma unroll
    for (int kc = 0; kc < 4; ++kc) {
        bf16x8 a = {0, 0, 0, 0, 0, 0, 0, 0};
        if (row < n) {
            if (FP32IN) {
                const float* H = (const float*)Hin;
                const float4* p = (const float4*)(H + (size_t)row * 128 + kc * 32 + q * 8);
                const float4 u0 = p[0];
                const float4 u1 = p[1];
                a[0] = (short)f2bf(u0.x); a[1] = (short)f2bf(u0.y);
                a[2] = (short)f2bf(u0.z); a[3] = (short)f2bf(u0.w);
                a[4] = (short)f2bf(u1.x); a[5] = (short)f2bf(u1.y);
                a[6] = (short)f2bf(u1.z); a[7] = (short)f2bf(u1.w);
            } else {
                const u16* H = (const u16*)Hin;
                a = *(const bf16x8*)(H + (size_t)row * 128 + kc * 32 + q * 8);
            }
        }
        afrag[kc] = a;
    }

    #pragma unroll 4
    for (int ct = 0; ct < DO / 16; ++ct) {
        f32x4 acc = {0.f, 0.f, 0.f, 0.f};
        #pragma unroll
        for (int kc = 0; kc < 4; ++kc) {
            const bf16x8 b = *(const bf16x8*)(Wb + (ct * 16 + m) * 128 + kc * 32 + q * 8);
            acc = __builtin_amdgcn_mfma_f32_16x16x32_bf16(afrag[kc], b, acc, 0, 0, 0);
        }
        #pragma unroll
        for (int r = 0; r < 4; ++r)
            sC[(w * 16 + q * 4 + r) * PADW + ct * 16 + m] = f2bf(acc[r]);
    }
    __syncthreads();

    const int g    = lane >> 2;
    const int cb   = (lane & 3) * (DO / 4);
    const int grow = blockIdx.x * 64 + w * 16 + g;
    if (grow < n) {
        #pragma unroll
        for (int i = 0; i < DO / 32; ++i) {
            const int4 v = *(const int4*)&sC[(w * 16 + g) * PADW + cb + i * 8];
            *(int4*)(Cb + (size_t)grow * DO + cb + i * 8) = v;
        }
    }
}

__global__ __launch_bounds__(256)
void wcvt_kernel(const float* __restrict__ W0, const float* __restrict__ W1,
                 const float* __restrict__ W2, u16* __restrict__ w0b,
                 u16* __restrict__ w1b, u16* __restrict__ w2b)
{
    const int i = blockIdx.x * 256 + threadIdx.x;
    if (i < 128 * 128) { w0b[i] = f2bf(W0[i]); w1b[i] = f2bf(W1[i]); }
    if (i < 64 * 128)  { w2b[i] = f2bf(W2[i]); }
}

// ---------------------------------------------------------------------------
// Phase 1: bucket partition + row histogram in one edge pass.
// Each block: LDS hist over 196 buckets gives per-edge rank; one global
// atomic per (block,bucket) reserves a contiguous run; writes to the bucket
// region are block-exclusive -> full-line coalescing in L2.
// ---------------------------------------------------------------------------
__global__ __launch_bounds__(256)
void part1_kernel(const int* __restrict__ erow, const int* __restrict__ ecol,
                  const float* __restrict__ eval, int* __restrict__ counts,
                  int* __restrict__ bcur, int2* __restrict__ part)
{
    __shared__ int shist[NBUCK];
    __shared__ int sbase[NBUCK];
    const int tid = threadIdx.x;
    for (int i = tid; i < NBUCK; i += 256) shist[i] = 0;
    __syncthreads();

    const int base = blockIdx.x * EPB;
    int rows[16], cols[16], rk[16];
    float vals[16];
    #pragma unroll
    for (int j = 0; j < 16; ++j) {
        const int e = base + j * 256 + tid;
        rows[j] = -1; cols[j] = 0; vals[j] = 0.f; rk[j] = 0;
        if (e < NE) {
            const int r = erow[e];
            rows[j] = r;
            cols[j] = ecol[e];
            vals[j] = eval[e];
            atomicAdd(&counts[r], 1);
            rk[j] = atomicAdd(&shist[r >> 9], 1);
        }
    }
    __syncthreads();
    for (int i = tid; i < NBUCK; i += 256)
        sbase[i] = shist[i] ? atomicAdd(&bcur[i], shist[i]) : 0;
    __syncthreads();
    #pragma unroll
    for (int j = 0; j < 16; ++j) {
        if (rows[j] >= 0) {
            const int b = rows[j] >> 9;
            const int pos = b * BCAP + sbase[b] + rk[j];
            part[pos] = make_int2(((rows[j] & 511) << 17) | cols[j],
                                  __float_as_int(vals[j]));
        }
    }
}

// ---------------------------------------------------------------------------
// Scans: 196 chunks of 512 rows.
// ---------------------------------------------------------------------------
__global__ __launch_bounds__(256)
void scan1_kernel(const int* __restrict__ counts, int* __restrict__ offs,
                  int* __restrict__ blockSums)
{
    __shared__ int sdata[256];
    const int tid = threadIdx.x;
    const int base = blockIdx.x * 512 + tid * 2;
    const int2 v = *(const int2*)&counts[base];
    const int tsum = v.x + v.y;
    sdata[tid] = tsum;
    __syncthreads();
    #pragma unroll
    for (int off = 1; off < 256; off <<= 1) {
        const int val = (tid >= off) ? sdata[tid - off] : 0;
        __syncthreads();
        sdata[tid] += val;
        __syncthreads();
    }
    const int excl = sdata[tid] - tsum;
    offs[base + 0] = excl;
    offs[base + 1] = excl + v.x;
    if (tid == 255) blockSums[blockIdx.x] = sdata[255];
}

__global__ __launch_bounds__(256)
void scan2_kernel(int* __restrict__ blockSums)
{
    __shared__ int sdata[256];
    const int tid = threadIdx.x;
    const int v = (tid < NBUCK) ? blockSums[tid] : 0;
    sdata[tid] = v;
    __syncthreads();
    #pragma unroll
    for (int off = 1; off < 256; off <<= 1) {
        const int val = (tid >= off) ? sdata[tid - off] : 0;
        __syncthreads();
        sdata[tid] += val;
        __syncthreads();
    }
    if (tid < NBUCK) blockSums[tid] = sdata[tid] - v;
}

__global__ __launch_bounds__(256)
void scan3_kernel(int* __restrict__ offs, const int* __restrict__ blockSums)
{
    const int i = blockIdx.x * 256 + threadIdx.x;
    if (i < PAD) offs[i] += blockSums[i >> 9];
}

// ---------------------------------------------------------------------------
// Phase 2: one WG per bucket; per-row cursors in LDS; scatter into the
// bucket's contiguous CSR slice (single-CU writes -> coalesced evictions).
// ---------------------------------------------------------------------------
__global__ __launch_bounds__(256)
void part2_kernel(const int* __restrict__ offs, const int* __restrict__ bcur,
                  const int2* __restrict__ part, int2* __restrict__ pce)
{
    __shared__ int lcur[512];
    const int b = blockIdx.x;
    const int tid = threadIdx.x;
    lcur[tid]       = offs[b * 512 + tid];
    lcur[tid + 256] = offs[b * 512 + 256 + tid];
    __syncthreads();
    const int cnt = bcur[b];
    const int2* src = part + (size_t)b * BCAP;
    for (int i = tid; i < cnt; i += 256) {
        const int2 ev = src[i];
        const int rl = ((u32)ev.x) >> 17;
        const int pos = atomicAdd(&lcur[rl], 1);
        pce[pos] = make_int2(ev.x & 0x1FFFF, ev.y);
    }
}

// ---------------------------------------------------------------------------
// CSR SpMM over bf16 features, fp32 accumulate. 16 lanes/row, 16 rows/block.
// MODE 1: Y_bf16 = relu(A H); MODE 2: += residual; MODE 3: Y_f32 = A H.
// ---------------------------------------------------------------------------
template<int LPC>
__device__ __forceinline__ void load_row(const u16* p, u32* u) {
    if constexpr (LPC == 8) {
        const uint4 t = *(const uint4*)p;
        u[0] = t.x; u[1] = t.y; u[2] = t.z; u[3] = t.w;
    } else {
        const uint2 t = *(const uint2*)p;
        u[0] = t.x; u[1] = t.y;
    }
}

template<int D, int MODE>
__global__ __launch_bounds__(256)
void spmm_csr(const int* __restrict__ offs, const int2* __restrict__ pce,
              const u16* __restrict__ Hb, void* __restrict__ Yv,
              const u16* __restrict__ Res)
{
    constexpr int LPC = D / 16;
    const int ln  = threadIdx.x & 15;
    const int row = blockIdx.x * 16 + (threadIdx.x >> 4);
    if (row >= NN) return;
    const int s = offs[row];
    const int t = offs[row + 1];
    const u16* hbase = Hb + ln * LPC;

    float a0[LPC], a1[LPC];
    #pragma unroll
    for (int j = 0; j < LPC; ++j) { a0[j] = 0.f; a1[j] = 0.f; }

    int e = s;
    for (; e + 1 < t; e += 2) {
        const int2 e0 = pce[e];
        const int2 e1 = pce[e + 1];
        const float v0 = __int_as_float(e0.y);
        const float v1 = __int_as_float(e1.y);
        u32 u0[LPC / 2], u1v[LPC / 2];
        load_row<LPC>(hbase + (size_t)e0.x * D, u0);
        load_row<LPC>(hbase + (size_t)e1.x * D, u1v);
        #pragma unroll
        for (int j = 0; j < LPC / 2; ++j) {
            a0[2*j]   = fmaf(v0, __uint_as_float(u0[j] << 16),          a0[2*j]);
            a0[2*j+1] = fmaf(v0, __uint_as_float(u0[j] & 0xffff0000u),  a0[2*j+1]);
            a1[2*j]   = fmaf(v1, __uint_as_float(u1v[j] << 16),         a1[2*j]);
            a1[2*j+1] = fmaf(v1, __uint_as_float(u1v[j] & 0xffff0000u), a1[2*j+1]);
        }
    }
    if (e < t) {
        const int2 e0 = pce[e];
        const float v0 = __int_as_float(e0.y);
        u32 u0[LPC / 2];
        load_row<LPC>(hbase + (size_t)e0.x * D, u0);
        #pragma unroll
        for (int j = 0; j < LPC / 2; ++j) {
            a0[2*j]   = fmaf(v0, __uint_as_float(u0[j] << 16),         a0[2*j]);
            a0[2*j+1] = fmaf(v0, __uint_as_float(u0[j] & 0xffff0000u), a0[2*j+1]);
        }
    }
    #pragma unroll
    for (int j = 0; j < LPC; ++j) a0[j] += a1[j];

    if constexpr (MODE == 3) {
        float* Y = (float*)Yv;
        *(float4*)(Y + (size_t)row * D + ln * LPC) =
            make_float4(a0[0], a0[1], a0[2], a0[3]);
    } else {
        if constexpr (MODE == 2) {
            u32 r[LPC / 2];
            load_row<LPC>(Res + (size_t)row * D + ln * LPC, r);
            #pragma unroll
            for (int j = 0; j < LPC / 2; ++j) {
                a0[2*j]   = fmaxf(a0[2*j],   0.f) + __uint_as_float(r[j] << 16);
                a0[2*j+1] = fmaxf(a0[2*j+1], 0.f) + __uint_as_float(r[j] & 0xffff0000u);
            }
        } else {
            #pragma unroll
            for (int j = 0; j < LPC; ++j) a0[j] = fmaxf(a0[j], 0.f);
        }
        u32 o[LPC / 2];
        #pragma unroll
        for (int j = 0; j < LPC / 2; ++j)
            o[j] = (u32)f2bf(a0[2*j]) | ((u32)f2bf(a0[2*j+1]) << 16);
        u16* Y = (u16*)Yv;
        if constexpr (LPC == 8)
            *(uint4*)(Y + (size_t)row * D + ln * LPC) = make_uint4(o[0], o[1], o[2], o[3]);
        else
            *(uint2*)(Y + (size_t)row * D + ln * LPC) = make_uint2(o[0], o[1]);
    }
}

extern "C" void kernel_launch(void* const* d_in, const int* in_sizes, int n_in,
                              void* d_out, int out_size, void* d_ws, size_t ws_size,
                              hipStream_t stream) {
    const float* x    = (const float*)d_in[0];
    const int*   erow = (const int*)  d_in[1];
    const int*   ecol = (const int*)  d_in[2];
    const float* eval = (const float*)d_in[3];
    const float* W0   = (const float*)d_in[4];
    const float* W1   = (const float*)d_in[5];
    const float* W2   = (const float*)d_in[6];
    float* out = (float*)d_out;

    char* p = (char*)d_ws;
    const size_t BUFB = (size_t)NN * 128 * sizeof(u16);   // 25.6 MB
    u16* tb   = (u16*)p;  p += BUFB;
    u16* h1b  = (u16*)p;  p += BUFB;
    u16* h2b  = (u16*)p;  p += BUFB;
    u16* w0b  = (u16*)p;  p += 128 * 128 * 2;
    u16* w1b  = (u16*)p;  p += 128 * 128 * 2;
    u16* w2b  = (u16*)p;  p += 64 * 128 * 2;
    int* counts = (int*)p; p += (size_t)PAD * 4;          // memset with bcur
    int* bcur   = (int*)p; p += 256 * 4;
    int* offs   = (int*)p; p += (size_t)PAD * 4;
    int* bsums  = (int*)p; p += 256 * 4;
    int2* part  = (int2*)p; p += (size_t)NBUCK * BCAP * 8;  // 16.06 MB
    int2* pce   = (int2*)p;                                 // 12.8 MB

    const dim3 blk(256);
    const int gemmBlocks  = (NN + 63) / 64;     // 1563
    const int spmmBlocks  = (NN + 15) / 16;     // 6250
    const int part1Blocks = (NE + EPB - 1) / EPB;  // 391

    // ---- CSR build ----
    hipMemsetAsync(counts, 0, ((size_t)PAD + 256) * 4, stream);  // counts + bcur
    part1_kernel<<<part1Blocks, blk, 0, stream>>>(erow, ecol, eval, counts, bcur, part);
    scan1_kernel<<<NBUCK, blk, 0, stream>>>(counts, offs, bsums);
    scan2_kernel<<<1, blk, 0, stream>>>(bsums);
    scan3_kernel<<<(PAD + 255) / 256, blk, 0, stream>>>(offs, bsums);
    part2_kernel<<<NBUCK, blk, 0, stream>>>(offs, bcur, part, pce);
    wcvt_kernel <<<64, blk, 0, stream>>>(W0, W1, W2, w0b, w1b, w2b);

    // ---- layers ----
    gemm_mfma<128, true ><<<gemmBlocks, blk, 0, stream>>>(x,   w0b, tb, NN);
    spmm_csr<128, 1><<<spmmBlocks, blk, 0, stream>>>(offs, pce, tb, h1b, nullptr);
    gemm_mfma<128, false><<<gemmBlocks, blk, 0, stream>>>(h1b, w1b, tb, NN);
    spmm_csr<128, 2><<<spmmBlocks, blk, 0, stream>>>(offs, pce, tb, h2b, h1b);
    gemm_mfma<64,  false><<<gemmBlocks, blk, 0, stream>>>(h2b, w2b, tb, NN);
    spmm_csr<64, 3><<<spmmBlocks, blk, 0, stream>>>(offs, pce, tb, out, nullptr);
}

// Round 5
// 428.877 us; speedup vs baseline: 16.2911x; 1.0893x over previous
//
#include <hip/hip_runtime.h>

// GCN on MI355X (gfx950). n=100000, 1.6M edges, D 128/128/64.
// Round 5: CSR build restructured.
//  part1: bucket partition ONLY (streaming two-pass, no register arrays ->
//         low VGPR / high occupancy; no per-row global atomics).
//  scanb: 196-entry exclusive scan of bucket totals.
//  part2: per-bucket LDS row-histogram + 512-wide LDS scan -> exact offs,
//         then LDS-cursor scatter into the bucket's contiguous CSR slice.
// GEMM (bf16 MFMA) and fused SpMM unchanged from round 3/4.

typedef unsigned int u32;
typedef unsigned short u16;
typedef __attribute__((ext_vector_type(8))) short bf16x8;
typedef __attribute__((ext_vector_type(4))) float f32x4;

constexpr int NN = 100000;
constexpr int NE = 1600000;
constexpr int PAD = 100352;            // 196 * 512
constexpr int NBUCK = 196;             // buckets of 512 rows
constexpr int BCAP = 10240;            // per-bucket capacity (mean 8163)
constexpr int EPB = 2048;              // edges per part1 block (8 per thread)

__device__ __forceinline__ u16 f2bf(float f) {   // RNE round to bf16
    u32 x = __float_as_uint(f);
    x += 0x7fffu + ((x >> 16) & 1u);
    return (u16)(x >> 16);
}

// ---------------------------------------------------------------------------
// GEMM: C_bf16[n x DO] = H @ W^T, mfma_f32_16x16x32_bf16, fp32 accum.
// ---------------------------------------------------------------------------
template<int DO, bool FP32IN>
__global__ __launch_bounds__(256)
void gemm_mfma(const void* __restrict__ Hin, const u16* __restrict__ Wb,
               u16* __restrict__ Cb, int n)
{
    constexpr int PADW = DO + 8;
    __shared__ u16 sC[4 * 16 * PADW];
    const int tid  = threadIdx.x;
    const int w    = tid >> 6;
    const int lane = tid & 63;
    const int m    = lane & 15;
    const int q    = lane >> 4;
    const int row  = blockIdx.x * 64 + w * 16 + m;

    bf16x8 afrag[4];
    #pragma unroll
    for (int kc = 0; kc < 4; ++kc) {
        bf16x8 a = {0, 0, 0, 0, 0, 0, 0, 0};
        if (row < n) {
            if (FP32IN) {
                const float* H = (const float*)Hin;
                const float4* p = (const float4*)(H + (size_t)row * 128 + kc * 32 + q * 8);
                const float4 u0 = p[0];
                const float4 u1 = p[1];
                a[0] = (short)f2bf(u0.x); a[1] = (short)f2bf(u0.y);
                a[2] = (short)f2bf(u0.z); a[3] = (short)f2bf(u0.w);
                a[4] = (short)f2bf(u1.x); a[5] = (short)f2bf(u1.y);
                a[6] = (short)f2bf(u1.z); a[7] = (short)f2bf(u1.w);
            } else {
                const u16* H = (const u16*)Hin;
                a = *(const bf16x8*)(H + (size_t)row * 128 + kc * 32 + q * 8);
            }
        }
        afrag[kc] = a;
    }

    #pragma unroll 4
    for (int ct = 0; ct < DO / 16; ++ct) {
        f32x4 acc = {0.f, 0.f, 0.f, 0.f};
        #pragma unroll
        for (int kc = 0; kc < 4; ++kc) {
            const bf16x8 b = *(const bf16x8*)(Wb + (ct * 16 + m) * 128 + kc * 32 + q * 8);
            acc = __builtin_amdgcn_mfma_f32_16x16x32_bf16(afrag[kc], b, acc, 0, 0, 0);
        }
        #pragma unroll
        for (int r = 0; r < 4; ++r)
            sC[(w * 16 + q * 4 + r) * PADW + ct * 16 + m] = f2bf(acc[r]);
    }
    __syncthreads();

    const int g    = lane >> 2;
    const int cb   = (lane & 3) * (DO / 4);
    const int grow = blockIdx.x * 64 + w * 16 + g;
    if (grow < n) {
        #pragma unroll
        for (int i = 0; i < DO / 32; ++i) {
            const int4 v = *(const int4*)&sC[(w * 16 + g) * PADW + cb + i * 8];
            *(int4*)(Cb + (size_t)grow * DO + cb + i * 8) = v;
        }
    }
}

__global__ __launch_bounds__(256)
void wcvt_kernel(const float* __restrict__ W0, const float* __restrict__ W1,
                 const float* __restrict__ W2, u16* __restrict__ w0b,
                 u16* __restrict__ w1b, u16* __restrict__ w2b)
{
    const int i = blockIdx.x * 256 + threadIdx.x;
    if (i < 128 * 128) { w0b[i] = f2bf(W0[i]); w1b[i] = f2bf(W1[i]); }
    if (i < 64 * 128)  { w2b[i] = f2bf(W2[i]); }
}

// ---------------------------------------------------------------------------
// part1: bucket partition, streaming (no per-edge register state).
// Pass A: LDS bucket histogram. Reserve contiguous runs via one global
// atomic per (block,bucket). Pass B: re-read edges (L1/L2-hit), rank via
// second LDS atomic pass, write packed (rowLocal<<17|col, val).
// ---------------------------------------------------------------------------
__global__ __launch_bounds__(256)
void part1_kernel(const int* __restrict__ erow, const int* __restrict__ ecol,
                  const float* __restrict__ eval, int* __restrict__ bcur,
                  int2* __restrict__ part)
{
    __shared__ int shist[NBUCK];
    __shared__ int sbase[NBUCK];
    const int tid = threadIdx.x;
    for (int i = tid; i < NBUCK; i += 256) shist[i] = 0;
    __syncthreads();

    const int base = blockIdx.x * EPB;
    #pragma unroll
    for (int j = 0; j < EPB / 256; ++j) {
        const int e = base + j * 256 + tid;
        if (e < NE) atomicAdd(&shist[erow[e] >> 9], 1);
    }
    __syncthreads();
    for (int i = tid; i < NBUCK; i += 256) {
        const int c = shist[i];
        sbase[i] = c ? atomicAdd(&bcur[i], c) : 0;
        shist[i] = 0;
    }
    __syncthreads();
    #pragma unroll
    for (int j = 0; j < EPB / 256; ++j) {
        const int e = base + j * 256 + tid;
        if (e < NE) {
            const int r = erow[e];
            const int b = r >> 9;
            const int rk = atomicAdd(&shist[b], 1);
            part[b * BCAP + sbase[b] + rk] =
                make_int2(((r & 511) << 17) | ecol[e], __float_as_int(eval[e]));
        }
    }
}

// Exclusive scan of 196 bucket totals (single block).
__global__ __launch_bounds__(256)
void scanb_kernel(const int* __restrict__ bcur, int* __restrict__ bbase)
{
    __shared__ int sdata[256];
    const int tid = threadIdx.x;
    const int v = (tid < NBUCK) ? bcur[tid] : 0;
    sdata[tid] = v;
    __syncthreads();
    #pragma unroll
    for (int off = 1; off < 256; off <<= 1) {
        const int val = (tid >= off) ? sdata[tid - off] : 0;
        __syncthreads();
        sdata[tid] += val;
        __syncthreads();
    }
    if (tid < NBUCK) bbase[tid] = sdata[tid] - v;
}

// ---------------------------------------------------------------------------
// part2: per-bucket row histogram (LDS) -> 512-wide LDS exclusive scan ->
// write offs (coalesced) -> LDS-cursor scatter into contiguous CSR slice.
// ---------------------------------------------------------------------------
__global__ __launch_bounds__(256)
void part2_kernel(const int* __restrict__ bcur, const int* __restrict__ bbase,
                  const int2* __restrict__ part, int* __restrict__ offs,
                  int2* __restrict__ pce)
{
    __shared__ int scnt[512];
    __shared__ int sdata[256];
    __shared__ int rowoff[512];
    const int b = blockIdx.x;
    const int tid = threadIdx.x;
    scnt[tid] = 0; scnt[tid + 256] = 0;
    __syncthreads();

    const int cnt = bcur[b];
    const int gb  = bbase[b];
    const int2* src = part + (size_t)b * BCAP;

    for (int i = tid; i < cnt; i += 256)
        atomicAdd(&scnt[((u32)src[i].x) >> 17], 1);
    __syncthreads();

    // 512-wide exclusive scan: pairs then Hillis-Steele over 256 pair-sums.
    const int c0 = scnt[2 * tid];
    const int c1 = scnt[2 * tid + 1];
    const int tsum = c0 + c1;
    sdata[tid] = tsum;
    __syncthreads();
    #pragma unroll
    for (int off = 1; off < 256; off <<= 1) {
        const int val = (tid >= off) ? sdata[tid - off] : 0;
        __syncthreads();
        sdata[tid] += val;
        __syncthreads();
    }
    const int excl = sdata[tid] - tsum;
    rowoff[2 * tid]     = gb + excl;
    rowoff[2 * tid + 1] = gb + excl + c0;
    __syncthreads();

    // offs for this bucket's 512 rows (rows >= NN get flat totals; offs[NN]
    // lands here too since PAD > NN).
    offs[b * 512 + tid]       = rowoff[tid];
    offs[b * 512 + 256 + tid] = rowoff[tid + 256];
    __syncthreads();

    for (int i = tid; i < cnt; i += 256) {
        const int2 ev = src[i];
        const int rl = ((u32)ev.x) >> 17;
        const int pos = atomicAdd(&rowoff[rl], 1);
        pce[pos] = make_int2(ev.x & 0x1FFFF, ev.y);
    }
}

// ---------------------------------------------------------------------------
// CSR SpMM over bf16 features, fp32 accumulate. 16 lanes/row, 16 rows/block.
// MODE 1: Y_bf16 = relu(A H); MODE 2: += residual; MODE 3: Y_f32 = A H.
// ---------------------------------------------------------------------------
template<int LPC>
__device__ __forceinline__ void load_row(const u16* p, u32* u) {
    if constexpr (LPC == 8) {
        const uint4 t = *(const uint4*)p;
        u[0] = t.x; u[1] = t.y; u[2] = t.z; u[3] = t.w;
    } else {
        const uint2 t = *(const uint2*)p;
        u[0] = t.x; u[1] = t.y;
    }
}

template<int D, int MODE>
__global__ __launch_bounds__(256)
void spmm_csr(const int* __restrict__ offs, const int2* __restrict__ pce,
              const u16* __restrict__ Hb, void* __restrict__ Yv,
              const u16* __restrict__ Res)
{
    constexpr int LPC = D / 16;
    const int ln  = threadIdx.x & 15;
    const int row = blockIdx.x * 16 + (threadIdx.x >> 4);
    if (row >= NN) return;
    const int s = offs[row];
    const int t = offs[row + 1];
    const u16* hbase = Hb + ln * LPC;

    float a0[LPC], a1[LPC];
    #pragma unroll
    for (int j = 0; j < LPC; ++j) { a0[j] = 0.f; a1[j] = 0.f; }

    int e = s;
    for (; e + 1 < t; e += 2) {
        const int2 e0 = pce[e];
        const int2 e1 = pce[e + 1];
        const float v0 = __int_as_float(e0.y);
        const float v1 = __int_as_float(e1.y);
        u32 u0[LPC / 2], u1v[LPC / 2];
        load_row<LPC>(hbase + (size_t)e0.x * D, u0);
        load_row<LPC>(hbase + (size_t)e1.x * D, u1v);
        #pragma unroll
        for (int j = 0; j < LPC / 2; ++j) {
            a0[2*j]   = fmaf(v0, __uint_as_float(u0[j] << 16),          a0[2*j]);
            a0[2*j+1] = fmaf(v0, __uint_as_float(u0[j] & 0xffff0000u),  a0[2*j+1]);
            a1[2*j]   = fmaf(v1, __uint_as_float(u1v[j] << 16),         a1[2*j]);
            a1[2*j+1] = fmaf(v1, __uint_as_float(u1v[j] & 0xffff0000u), a1[2*j+1]);
        }
    }
    if (e < t) {
        const int2 e0 = pce[e];
        const float v0 = __int_as_float(e0.y);
        u32 u0[LPC / 2];
        load_row<LPC>(hbase + (size_t)e0.x * D, u0);
        #pragma unroll
        for (int j = 0; j < LPC / 2; ++j) {
            a0[2*j]   = fmaf(v0, __uint_as_float(u0[j] << 16),         a0[2*j]);
            a0[2*j+1] = fmaf(v0, __uint_as_float(u0[j] & 0xffff0000u), a0[2*j+1]);
        }
    }
    #pragma unroll
    for (int j = 0; j < LPC; ++j) a0[j] += a1[j];

    if constexpr (MODE == 3) {
        float* Y = (float*)Yv;
        *(float4*)(Y + (size_t)row * D + ln * LPC) =
            make_float4(a0[0], a0[1], a0[2], a0[3]);
    } else {
        if constexpr (MODE == 2) {
            u32 r[LPC / 2];
            load_row<LPC>(Res + (size_t)row * D + ln * LPC, r);
            #pragma unroll
            for (int j = 0; j < LPC / 2; ++j) {
                a0[2*j]   = fmaxf(a0[2*j],   0.f) + __uint_as_float(r[j] << 16);
                a0[2*j+1] = fmaxf(a0[2*j+1], 0.f) + __uint_as_float(r[j] & 0xffff0000u);
            }
        } else {
            #pragma unroll
            for (int j = 0; j < LPC; ++j) a0[j] = fmaxf(a0[j], 0.f);
        }
        u32 o[LPC / 2];
        #pragma unroll
        for (int j = 0; j < LPC / 2; ++j)
            o[j] = (u32)f2bf(a0[2*j]) | ((u32)f2bf(a0[2*j+1]) << 16);
        u16* Y = (u16*)Yv;
        if constexpr (LPC == 8)
            *(uint4*)(Y + (size_t)row * D + ln * LPC) = make_uint4(o[0], o[1], o[2], o[3]);
        else
            *(uint2*)(Y + (size_t)row * D + ln * LPC) = make_uint2(o[0], o[1]);
    }
}

extern "C" void kernel_launch(void* const* d_in, const int* in_sizes, int n_in,
                              void* d_out, int out_size, void* d_ws, size_t ws_size,
                              hipStream_t stream) {
    const float* x    = (const float*)d_in[0];
    const int*   erow = (const int*)  d_in[1];
    const int*   ecol = (const int*)  d_in[2];
    const float* eval = (const float*)d_in[3];
    const float* W0   = (const float*)d_in[4];
    const float* W1   = (const float*)d_in[5];
    const float* W2   = (const float*)d_in[6];
    float* out = (float*)d_out;

    char* p = (char*)d_ws;
    const size_t BUFB = (size_t)NN * 128 * sizeof(u16);   // 25.6 MB
    u16* tb   = (u16*)p;  p += BUFB;
    u16* h1b  = (u16*)p;  p += BUFB;
    u16* h2b  = (u16*)p;  p += BUFB;
    u16* w0b  = (u16*)p;  p += 128 * 128 * 2;
    u16* w1b  = (u16*)p;  p += 128 * 128 * 2;
    u16* w2b  = (u16*)p;  p += 64 * 128 * 2;
    int* bcur   = (int*)p; p += 256 * 4;                  // bucket totals
    int* bbase  = (int*)p; p += 256 * 4;                  // bucket prefix
    int* offs   = (int*)p; p += ((size_t)PAD + 256) * 4;
    int2* part  = (int2*)p; p += (size_t)NBUCK * BCAP * 8;  // 16.06 MB
    int2* pce   = (int2*)p;                                 // 12.8 MB

    const dim3 blk(256);
    const int gemmBlocks  = (NN + 63) / 64;        // 1563
    const int spmmBlocks  = (NN + 15) / 16;        // 6250
    const int part1Blocks = (NE + EPB - 1) / EPB;  // 782

    // ---- CSR build ----
    hipMemsetAsync(bcur, 0, 256 * 4, stream);
    part1_kernel<<<part1Blocks, blk, 0, stream>>>(erow, ecol, eval, bcur, part);
    scanb_kernel<<<1, blk, 0, stream>>>(bcur, bbase);
    part2_kernel<<<NBUCK, blk, 0, stream>>>(bcur, bbase, part, offs, pce);
    wcvt_kernel <<<64, blk, 0, stream>>>(W0, W1, W2, w0b, w1b, w2b);

    // ---- layers ----
    gemm_mfma<128, true ><<<gemmBlocks, blk, 0, stream>>>(x,   w0b, tb, NN);
    spmm_csr<128, 1><<<spmmBlocks, blk, 0, stream>>>(offs, pce, tb, h1b, nullptr);
    gemm_mfma<128, false><<<gemmBlocks, blk, 0, stream>>>(h1b, w1b, tb, NN);
    spmm_csr<128, 2><<<spmmBlocks, blk, 0, stream>>>(offs, pce, tb, h2b, h1b);
    gemm_mfma<64,  false><<<gemmBlocks, blk, 0, stream>>>(h2b, w2b, tb, NN);
    spmm_csr<64, 3><<<spmmBlocks, blk, 0, stream>>>(offs, pce, tb, out, nullptr);
}